// Round 18
// baseline (69.028 us; speedup 1.0000x reference)
//
#include <hip/hip_runtime.h>
#include <hip/hip_bf16.h>
#include <stdint.h>

// Problem constants
#define NB   4096      // rows per input matrix
#define DTOT 256       // feature dim
#define NTOT 8192      // 2*NB
#define NBLK2 128      // 8192 / 64 tile blocks per side (64-wide wave tiles)
#define NTRI2 (NBLK2 * (NBLK2 + 1) / 2)   // 8256 wave tiles
#define NGRID (NTRI2 / 4)                 // 2064 blocks (4 indep waves each), %8==0
#define NXCD 8
#define CPX2 (NGRID / NXCD)               // 258

// Workspace layout (bytes):  [first 2048 bytes zeroed by hipMemsetAsync each launch]
//   wsd[0..32)    S partial slots   (sum of row sq-norms)
//   wsd[32..64)   Sw partial slots  (sum of sigmoid(|s1-s2|))
//   wsd[64..160)  acc slots: [q*32 + s], q=0:XX 1:YY 2:XY+YX
//   ws+4096       float sq[8192]            (32 KB)
//   ws+36864      ushort tot[8192*256] bf16 (4 MB)
#define WSD_S     0
#define WSD_SW    32
#define WSD_ACC   64
#define WS_SQ_OFF  4096
#define WS_TOT_OFF 36864

typedef __attribute__((ext_vector_type(8))) short bf16x8;
typedef __attribute__((ext_vector_type(4))) float f32x4;

__device__ __forceinline__ unsigned short f2bf(float f) {
    unsigned int u = __float_as_uint(f);
    unsigned int r = (u + 0x7FFFu + ((u >> 16) & 1u)) >> 16;   // RNE
    return (unsigned short)r;
}

// ---------------- kernel A: row sq-norms + bf16 convert + slot partials ----------------
__global__ __launch_bounds__(256) void k_rows(const float* __restrict__ src,
                                              const float* __restrict__ tgt,
                                              const float* __restrict__ s1,
                                              const float* __restrict__ s2,
                                              float* __restrict__ sq,
                                              unsigned short* __restrict__ tot,
                                              double* __restrict__ wsd) {
    __shared__ double sred[4];
    int tid  = threadIdx.x;
    int lane = tid & 63;
    int wid  = tid >> 6;
    int r = blockIdx.x * 4 + wid;
    const float* p = (r < NB) ? (src + (size_t)r * DTOT)
                              : (tgt + (size_t)(r - NB) * DTOT);
    float4 v = *(const float4*)(p + lane * 4);
    float s = v.x * v.x + v.y * v.y + v.z * v.z + v.w * v.w;
    ushort4 u;
    u.x = f2bf(v.x); u.y = f2bf(v.y); u.z = f2bf(v.z); u.w = f2bf(v.w);
    *(ushort4*)(tot + (size_t)r * DTOT + lane * 4) = u;
    for (int off = 32; off; off >>= 1) s += __shfl_down(s, off, 64);
    if (lane == 0) { sq[r] = s; sred[wid] = (double)s; }
    __syncthreads();
    if (tid == 0) {
        atomicAdd(&wsd[WSD_S + (blockIdx.x & 31)],
                  sred[0] + sred[1] + sred[2] + sred[3]);
        if (blockIdx.x < NB / 4) {
            float sw = 0.0f;
#pragma unroll
            for (int j = 0; j < 4; ++j) {
                int i = blockIdx.x * 4 + j;
                float d = fabsf(s1[i] - s2[i]);
                sw += 1.0f / (1.0f + exp2f(-d * 1.442695041f));
            }
            atomicAdd(&wsd[WSD_SW + (blockIdx.x & 31)], (double)sw);
        }
    }
}

// ---------------- kernel C: fused GEMM + RBF epilogue, BARRIER-FREE waves -------------
// 4 independent waves/block; wave w owns one 64x64 upper-tri tile and a private 8 KB LDS
// slice (A 4KB + B 4KB, BK=32 single buffer). NO s_barrier / __syncthreads anywhere:
// per-wave vmcnt(0) waits its own 8 global_load_lds; lgkmcnt(0) before re-stage protects
// LDS read-before-overwrite. Waves slip freely -> pipes (MFMA/VALU/LDS) fill across the
// 16 resident waves/CU instead of convoying at 2 barriers per K-step (R8..R17 structure,
// stuck at ~35us vs ~13us pipe floor).
// LDS packing per matrix: [32 rows][8 chunks of 16B]; logical row r (0..63), 16B k-chunk
// kc (0..3) stored at LDS row r>>1, chunk ((r&1)*4+kc) ^ ((r>>1)&7). Fragment reads hit
// each chunk slot exactly 2x -> bank-conflict-free (2-way is free, m136). Swizzle is
// carried on the per-lane GLOBAL source address (rule 21); global_load_lds dest linear.
// HARD-WON LESSONS — do not reintroduce:
//   R6/R7: launch_bounds min-waves arg -> accumulator spill.  R11: 512-thr -> VGPR 36.
//   R12: per-thread __threadfence ticket -> L2 flush storm.
//   R9: sched_barrier cages on a barrier-synced loop -> order-pinning regression.
__global__ __launch_bounds__(256) void k_mmd(const unsigned short* __restrict__ tot,
                                             const float* __restrict__ sq,
                                             double* __restrict__ wsd) {
    __shared__ unsigned short lds[4][2][2048];   // [wave][A=0,B=1][32 rows x 64 shorts]

    const int tid  = threadIdx.x;
    const int lane = tid & 63;
    const int wid  = tid >> 6;

    // T1 XCD-chunked swizzle on block index, then per-wave tri-tile decode (64-granular)
    const int tg = (blockIdx.x % NXCD) * CPX2 + blockIdx.x / NXCD;
    const int t  = tg * 4 + wid;
    int I = (int)((2.0f * NBLK2 + 1.0f
                   - sqrtf((2.0f * NBLK2 + 1.0f) * (2.0f * NBLK2 + 1.0f) - 8.0f * (float)t)) * 0.5f);
    while (I > 0 && I * (2 * NBLK2 - I + 1) / 2 > t) --I;
    while ((I + 1) * (2 * NBLK2 - I) / 2 <= t) ++I;
    const int J = I + (t - I * (2 * NBLK2 - I + 1) / 2);
    const int brow = I * 64;
    const int bcol = J * 64;

    const unsigned short* gA = tot + (size_t)brow * DTOT;
    const unsigned short* gB = tot + (size_t)bcol * DTOT;
    unsigned short* ldsA = &lds[wid][0][0];
    unsigned short* ldsB = &lds[wid][1][0];

    f32x4 acc[4][4] = {};

    // ---- staging geometry (lane-const): load s covers LDS rows s*8..+8 of one matrix.
    // lane l -> LDS row s*8+(l>>3), stored chunk l&7; logical G=(l&7)^(l>>3 & 7):
    // logical row r = 2*(s*8 + lr) + (G>>2), k-chunk (G&3). srcOff(s) = base + s*4096.
    {
    }
    const int lr  = (lane >> 3) & 7;
    const int G   = (lane & 7) ^ lr;
    const size_t srcBase = (size_t)(2 * lr + (G >> 2)) * DTOT + (G & 3) * 8;

#define STAGE(ki_)                                                                \
    do {                                                                          \
        const size_t kOff_ = srcBase + (ki_) * 32;                                \
        _Pragma("unroll")                                                         \
        for (int s_ = 0; s_ < 4; ++s_)                                            \
            __builtin_amdgcn_global_load_lds(                                     \
                (const __attribute__((address_space(1))) void*)(gA + kOff_ + s_ * 16 * DTOT), \
                (__attribute__((address_space(3))) void*)(ldsA + s_ * 512), 16, 0, 0); \
        _Pragma("unroll")                                                         \
        for (int s_ = 0; s_ < 4; ++s_)                                            \
            __builtin_amdgcn_global_load_lds(                                     \
                (const __attribute__((address_space(1))) void*)(gB + kOff_ + s_ * 16 * DTOT), \
                (__attribute__((address_space(3))) void*)(ldsB + s_ * 512), 16, 0, 0); \
    } while (0)

    // ---- fragment read geometry (lane-const, step-invariant): af[mi] lane l =
    // A[mi*16 + (l&15)][(l>>4)*8..+8]: LDS row mi*8 + h (h=(l&15)>>1),
    // chunk (((l&1)*4 + (l>>4)) ^ h). Offset in shorts: mi*512 + h*64 + sc*8.
    const int h  = (lane & 15) >> 1;
    const int sc = (((lane & 1) * 4) + (lane >> 4)) ^ h;
    const int rd0 = h * 64 + sc * 8;

    STAGE(0);
#pragma unroll
    for (int ki = 0; ki < 8; ++ki) {
        asm volatile("s_waitcnt vmcnt(0)" ::: "memory");   // own 8 loads landed
        __builtin_amdgcn_sched_barrier(0);
        bf16x8 af[4], bfr[4];
#pragma unroll
        for (int mi = 0; mi < 4; ++mi) af[mi]  = *(const bf16x8*)(ldsA + rd0 + mi * 512);
#pragma unroll
        for (int ni = 0; ni < 4; ++ni) bfr[ni] = *(const bf16x8*)(ldsB + rd0 + ni * 512);
#pragma unroll
        for (int mi = 0; mi < 4; ++mi)
#pragma unroll
            for (int ni = 0; ni < 4; ++ni)
                acc[mi][ni] = __builtin_amdgcn_mfma_f32_16x16x32_bf16(
                    af[mi], bfr[ni], acc[mi][ni], 0, 0, 0);
        if (ki < 7) {
            asm volatile("s_waitcnt lgkmcnt(0)" ::: "memory");  // reads done before overwrite
            __builtin_amdgcn_sched_barrier(0);
            STAGE(ki + 1);
        }
    }
#undef STAGE

    // ---- derive bandwidth scale from S-slots (per-wave) ----
    double sv = (lane < 32) ? wsd[WSD_S + lane] : 0.0;
#pragma unroll
    for (int off = 32; off; off >>= 1) sv += __shfl_down(sv, off, 64);
    sv = __shfl(sv, 0, 64);                          // S total, broadcast
    const float c = (float)(1.4426950408889634
                            * ((double)NTOT * (double)NTOT - (double)NTOT)
                            / (8.0 * (double)NTOT * sv));
    const float c2 = 2.0f * c;

    // ---- fused epilogue: L2 -> 5-bandwidth RBF sum -> per-wave quadrant atomic ----
    float sqjc[4], sqic[16];
#pragma unroll
    for (int ni = 0; ni < 4; ++ni)
        sqjc[ni] = sq[bcol + ni * 16 + (lane & 15)] * c;
#pragma unroll
    for (int mi = 0; mi < 4; ++mi)
#pragma unroll
        for (int r = 0; r < 4; ++r)
            sqic[mi * 4 + r] = sq[brow + mi * 16 + (lane >> 4) * 4 + r] * c;

    float part = 0.0f;
#pragma unroll
    for (int mi = 0; mi < 4; ++mi) {
#pragma unroll
        for (int ni = 0; ni < 4; ++ni) {
#pragma unroll
            for (int r = 0; r < 4; ++r) {
                float s  = sqic[mi * 4 + r] + sqjc[ni];
                float tn = fminf(__builtin_fmaf(c2, acc[mi][ni][r], -s), 0.0f);
                float k4 = __builtin_amdgcn_exp2f(tn);     // raw v_exp_f32
                float k3 = k4 * k4;
                float k2 = k3 * k3;
                float k1 = k2 * k2;
                float k0 = k1 * k1;
                part += ((k4 + k3) + (k2 + k1)) + k0;
            }
        }
    }
    for (int off = 32; off; off >>= 1) part += __shfl_down(part, off, 64);
    if (lane == 0) {
        double tsum = (double)part;
        if (I != J) tsum *= 2.0;                       // transpose tile identical
        int qi = (brow < NB) ? ((bcol < NB) ? 0 : 2) : 1;
        atomicAdd(&wsd[WSD_ACC + qi * 32 + (t & 31)], tsum);
    }
}

// ---------------- kernel D: finalize (wfac from Sw-slots, then acc reduce) ------------
__global__ __launch_bounds__(128) void k_final(const double* __restrict__ wsd,
                                               float* __restrict__ out) {
    __shared__ double sred[128];
    int t = threadIdx.x;
    sred[t] = (t < 32) ? wsd[WSD_SW + t] : 0.0;
    __syncthreads();
    for (int off = 64; off; off >>= 1) { if (t < off) sred[t] += sred[t + off]; __syncthreads(); }
    double Sw = sred[0];
    double SW = Sw * Sw;
    double wfac = SW / (SW + 1e-8);
    __syncthreads();
    double v = 0.0;
    if (t < 96) {
        v = wsd[WSD_ACC + t];
        if (t < 32)       v *= wfac;    // XX weighted
        else if (t >= 64) v = -v;       // -(XY+YX)
    }
    sred[t] = v; __syncthreads();
    for (int off = 64; off; off >>= 1) { if (t < off) sred[t] += sred[t + off]; __syncthreads(); }
    if (t == 0) {
        double inv = 1.0 / ((double)NB * (double)NB);
        out[0] = (float)(sred[0] * inv);
    }
}

extern "C" void kernel_launch(void* const* d_in, const int* in_sizes, int n_in,
                              void* d_out, int out_size, void* d_ws, size_t ws_size,
                              hipStream_t stream) {
    const float* src = (const float*)d_in[0];
    const float* tgt = (const float*)d_in[1];
    const float* s1  = (const float*)d_in[2];
    const float* s2  = (const float*)d_in[3];
    float* out = (float*)d_out;

    char* ws = (char*)d_ws;
    double* wsd = (double*)ws;
    float* sq = (float*)(ws + WS_SQ_OFF);
    unsigned short* tot = (unsigned short*)(ws + WS_TOT_OFF);

    // Zero slot header every call (harness poisons d_ws with 0xAA — R10 lesson).
    hipMemsetAsync(ws, 0, 2048, stream);

    hipLaunchKernelGGL(k_rows, dim3(NTOT/4), dim3(256), 0, stream,
                       src, tgt, s1, s2, sq, tot, wsd);
    hipLaunchKernelGGL(k_mmd,  dim3(NGRID),  dim3(256), 0, stream, tot, sq, wsd);
    hipLaunchKernelGGL(k_final, dim3(1),     dim3(128), 0, stream, wsd, out);
}

// Round 19
// 60.291 us; speedup vs baseline: 1.1449x; 1.1449x over previous
//
#include <hip/hip_runtime.h>
#include <hip/hip_bf16.h>
#include <stdint.h>

// Problem constants
#define NB   4096      // rows per input matrix
#define DTOT 256       // feature dim
#define NTOT 8192      // 2*NB
#define NBLK 64        // 8192 / 128 tile blocks per side
#define NTRI (NBLK * (NBLK + 1) / 2)   // 2080, divisible by 8
#define NXCD 8
#define CPX  (NTRI / NXCD)             // 260 tiles per XCD

// Workspace layout (bytes):  [first 2048 bytes zeroed by hipMemsetAsync each launch]
//   wsd[0..32)    S partial slots   (sum of row sq-norms)
//   wsd[32..64)   Sw partial slots  (sum of sigmoid(|s1-s2|))
//   wsd[64..160)  acc slots: [q*32 + s], q=0:XX 1:YY 2:XY+YX
//   ws+4096       float sq[8192]            (32 KB)
//   ws+36864      ushort tot[8192*256] bf16 (4 MB)
#define WSD_S     0
#define WSD_SW    32
#define WSD_ACC   64
#define WS_SQ_OFF  4096
#define WS_TOT_OFF 36864

typedef __attribute__((ext_vector_type(8))) short bf16x8;
typedef __attribute__((ext_vector_type(4))) float f32x4;

__device__ __forceinline__ unsigned short f2bf(float f) {
    unsigned int u = __float_as_uint(f);
    unsigned int r = (u + 0x7FFFu + ((u >> 16) & 1u)) >> 16;   // RNE
    return (unsigned short)r;
}

// ---------------- kernel A: row sq-norms + bf16 convert + slot partials ----------------
__global__ __launch_bounds__(256) void k_rows(const float* __restrict__ src,
                                              const float* __restrict__ tgt,
                                              const float* __restrict__ s1,
                                              const float* __restrict__ s2,
                                              float* __restrict__ sq,
                                              unsigned short* __restrict__ tot,
                                              double* __restrict__ wsd) {
    __shared__ double sred[4];
    int tid  = threadIdx.x;
    int lane = tid & 63;
    int wid  = tid >> 6;
    int r = blockIdx.x * 4 + wid;
    const float* p = (r < NB) ? (src + (size_t)r * DTOT)
                              : (tgt + (size_t)(r - NB) * DTOT);
    float4 v = *(const float4*)(p + lane * 4);
    float s = v.x * v.x + v.y * v.y + v.z * v.z + v.w * v.w;
    ushort4 u;
    u.x = f2bf(v.x); u.y = f2bf(v.y); u.z = f2bf(v.z); u.w = f2bf(v.w);
    *(ushort4*)(tot + (size_t)r * DTOT + lane * 4) = u;
    for (int off = 32; off; off >>= 1) s += __shfl_down(s, off, 64);
    if (lane == 0) { sq[r] = s; sred[wid] = (double)s; }
    __syncthreads();
    if (tid == 0) {
        atomicAdd(&wsd[WSD_S + (blockIdx.x & 31)],
                  sred[0] + sred[1] + sred[2] + sred[3]);
        if (blockIdx.x < NB / 4) {
            float sw = 0.0f;
#pragma unroll
            for (int j = 0; j < 4; ++j) {
                int i = blockIdx.x * 4 + j;
                float d = fabsf(s1[i] - s2[i]);
                sw += 1.0f / (1.0f + exp2f(-d * 1.442695041f));
            }
            atomicAdd(&wsd[WSD_SW + (blockIdx.x & 31)], (double)sw);
        }
    }
}

// ---------------- kernel C: fused GEMM + RBF epilogue, upper-tri ----------------------
// R17-proven structure (57.5 us total — the measured best of all 7 structural families):
// BK=32 double-buffered pipeline at FULL occupancy. LDS = 2 bufs x (A+B) x 128x32 bf16
// = 32 KB -> 4 blocks/CU. 8 K-steps; each issues next step's 4 global_load_lds then
// waits vmcnt(4) (counted: new loads fly across the barrier under current MFMAs).
// R19 micro-reordering: bandwidth constant (S-slot reduce) and the 20 sq[] epilogue
// inputs are computed BEFORE the K-loop, hiding their L2 latency under prologue staging
// (+~20 live VGPR, same occupancy bucket per 64/128 VGPR steps).
// LDS packing: logical (r,c4) r=0..127, chunk c4=0..3 -> LDS row r&63, chunk
// ((r>>6)*4+c4)^((r&63)&7): 8-chunk XOR geometry, 2-way-free. Swizzle on per-lane
// global SOURCE (rule 21), linear global_load_lds dest, matching XOR on ds_read.
// T1 XCD-chunked blockIdx swizzle kept (R15).
// HARD-WON LESSONS — do not reintroduce:
//   R6/R7: launch_bounds min-waves arg -> accumulator spill.  R11: 512-thr -> VGPR 36.
//   R12: per-thread __threadfence ticket -> L2 flush storm.   R18: barrier-free single-
//   buffer waves -> full latency exposure every K-step (51 us).
__global__ __launch_bounds__(256) void k_mmd(const unsigned short* __restrict__ tot,
                                             const float* __restrict__ sq,
                                             double* __restrict__ wsd) {
    __shared__ unsigned short lds[2][2][64 * 64];   // [buf][A=0,B=1][rr*64 + chunk*8]

    // T1: XCD-chunked swizzle, then decode upper-triangular index t -> (bi, bj), bi <= bj
    const int t = (blockIdx.x % NXCD) * CPX + blockIdx.x / NXCD;
    int bi = (int)((2.0f * NBLK + 1.0f
                    - sqrtf((2.0f * NBLK + 1.0f) * (2.0f * NBLK + 1.0f) - 8.0f * (float)t)) * 0.5f);
    while (bi > 0 && bi * (2 * NBLK - bi + 1) / 2 > t) --bi;
    while ((bi + 1) * (2 * NBLK - bi) / 2 <= t) ++bi;
    const int bj = bi + (t - bi * (2 * NBLK - bi + 1) / 2);

    const int tid  = threadIdx.x;
    const int lane = tid & 63;
    const int wid  = tid >> 6;
    const int wm = wid >> 1, wn = wid & 1;
    const int brow = bi * 128;
    const int bcol = bj * 128;

    const unsigned short* gA = tot + (size_t)brow * DTOT;
    const unsigned short* gB = tot + (size_t)bcol * DTOT;

    f32x4 acc[4][4] = {};

    // ---- per-lane staging geometry (ki-invariant) ----
    int rr_0 = (wid * 2 + 0) * 8 + (lane >> 3);
    int g_0  = (lane & 7) ^ (rr_0 & 7);
    const size_t srcOff0 = (size_t)(rr_0 + 64 * (g_0 >> 2)) * DTOT + (g_0 & 3) * 8;
    const int dst0 = (wid * 2 + 0) * 8 * 64;
    int rr_1 = (wid * 2 + 1) * 8 + (lane >> 3);
    int g_1  = (lane & 7) ^ (rr_1 & 7);
    const size_t srcOff1 = (size_t)(rr_1 + 64 * (g_1 >> 2)) * DTOT + (g_1 & 3) * 8;
    const int dst1 = (wid * 2 + 1) * 8 * 64;

#define STAGE(buf, ki_)                                                           \
    do {                                                                          \
        const int c0_ = (ki_) * 32;                                               \
        __builtin_amdgcn_global_load_lds(                                         \
            (const __attribute__((address_space(1))) void*)(gA + srcOff0 + c0_),  \
            (__attribute__((address_space(3))) void*)(&lds[buf][0][dst0]), 16, 0, 0); \
        __builtin_amdgcn_global_load_lds(                                         \
            (const __attribute__((address_space(1))) void*)(gA + srcOff1 + c0_),  \
            (__attribute__((address_space(3))) void*)(&lds[buf][0][dst1]), 16, 0, 0); \
        __builtin_amdgcn_global_load_lds(                                         \
            (const __attribute__((address_space(1))) void*)(gB + srcOff0 + c0_),  \
            (__attribute__((address_space(3))) void*)(&lds[buf][1][dst0]), 16, 0, 0); \
        __builtin_amdgcn_global_load_lds(                                         \
            (const __attribute__((address_space(1))) void*)(gB + srcOff1 + c0_),  \
            (__attribute__((address_space(3))) void*)(&lds[buf][1][dst1]), 16, 0, 0); \
    } while (0)

    // ---- per-lane read geometry (ki-invariant LDS offsets, in shorts) ----
    int rdA[4], rdB[4];
#pragma unroll
    for (int mi = 0; mi < 4; ++mi) {
        int rr = mi * 16 + (lane & 15);
        rdA[mi] = rr * 64 + (((wm * 4 + (lane >> 4)) ^ (rr & 7)) * 8);
        rdB[mi] = rr * 64 + (((wn * 4 + (lane >> 4)) ^ (rr & 7)) * 8);
    }

    STAGE(0, 0);                       // prologue: 4 loads in flight

    // ---- epilogue constants derived NOW: their L2/shfl latency hides under staging ----
    double sv = (lane < 32) ? wsd[WSD_S + lane] : 0.0;
#pragma unroll
    for (int off = 32; off; off >>= 1) sv += __shfl_down(sv, off, 64);
    sv = __shfl(sv, 0, 64);                          // S total, broadcast
    const float c = (float)(1.4426950408889634
                            * ((double)NTOT * (double)NTOT - (double)NTOT)
                            / (8.0 * (double)NTOT * sv));
    const float c2 = 2.0f * c;
    float sqjc[4], sqic[16];
#pragma unroll
    for (int ni = 0; ni < 4; ++ni)
        sqjc[ni] = sq[bcol + wn * 64 + ni * 16 + (lane & 15)] * c;
#pragma unroll
    for (int mi = 0; mi < 4; ++mi)
#pragma unroll
        for (int r = 0; r < 4; ++r)
            sqic[mi * 4 + r] = sq[brow + wm * 64 + mi * 16 + (lane >> 4) * 4 + r] * c;

#pragma unroll
    for (int ki = 0; ki < 8; ++ki) {
        const int cur = ki & 1;
        if (ki < 7) {
            STAGE(cur ^ 1, ki + 1);    // 4 more in flight (other buffer)
            asm volatile("s_waitcnt vmcnt(4)" ::: "memory");   // current step landed
        } else {
            asm volatile("s_waitcnt vmcnt(0)" ::: "memory");
        }
        __builtin_amdgcn_sched_barrier(0);
        __builtin_amdgcn_s_barrier();          // raw: no implicit vmcnt(0) drain

        const unsigned short* la = &lds[cur][0][0];
        const unsigned short* lb = &lds[cur][1][0];
        bf16x8 af[4], bfr[4];
#pragma unroll
        for (int mi = 0; mi < 4; ++mi) af[mi]  = *(const bf16x8*)(la + rdA[mi]);
#pragma unroll
        for (int ni = 0; ni < 4; ++ni) bfr[ni] = *(const bf16x8*)(lb + rdB[ni]);
#pragma unroll
        for (int mi = 0; mi < 4; ++mi)
#pragma unroll
            for (int ni = 0; ni < 4; ++ni)
                acc[mi][ni] = __builtin_amdgcn_mfma_f32_16x16x32_bf16(
                    af[mi], bfr[ni], acc[mi][ni], 0, 0, 0);

        __builtin_amdgcn_s_barrier();          // all waves done reading lds[cur]
    }
#undef STAGE

    // ---- fused epilogue: L2 -> 5-bandwidth RBF sum -> quadrant accumulate ----
    float part = 0.0f;
#pragma unroll
    for (int mi = 0; mi < 4; ++mi) {
#pragma unroll
        for (int ni = 0; ni < 4; ++ni) {
#pragma unroll
            for (int r = 0; r < 4; ++r) {
                float s  = sqic[mi * 4 + r] + sqjc[ni];
                float tn = fminf(__builtin_fmaf(c2, acc[mi][ni][r], -s), 0.0f);
                float k4 = __builtin_amdgcn_exp2f(tn);     // raw v_exp_f32
                float k3 = k4 * k4;
                float k2 = k3 * k3;
                float k1 = k2 * k2;
                float k0 = k1 * k1;
                part += ((k4 + k3) + (k2 + k1)) + k0;
            }
        }
    }
    for (int off = 32; off; off >>= 1) part += __shfl_down(part, off, 64);

    // block reduce: alias scratch into lds (free after the loop's final barrier)
    double* blkred = (double*)&lds[0][0][0];
    if (lane == 0) blkred[wid] = (double)part;
    __syncthreads();
    if (tid == 0) {
        double tsum = blkred[0] + blkred[1] + blkred[2] + blkred[3];
        if (bi != bj) tsum *= 2.0;                     // transpose block identical
        int qi = (brow < NB) ? ((bcol < NB) ? 0 : 2) : 1;
        atomicAdd(&wsd[WSD_ACC + qi * 32 + (t & 31)], tsum);
    }
}

// ---------------- kernel D: finalize (wfac from Sw-slots, then acc reduce) ------------
__global__ __launch_bounds__(128) void k_final(const double* __restrict__ wsd,
                                               float* __restrict__ out) {
    __shared__ double sred[128];
    int t = threadIdx.x;
    sred[t] = (t < 32) ? wsd[WSD_SW + t] : 0.0;
    __syncthreads();
    for (int off = 64; off; off >>= 1) { if (t < off) sred[t] += sred[t + off]; __syncthreads(); }
    double Sw = sred[0];
    double SW = Sw * Sw;
    double wfac = SW / (SW + 1e-8);
    __syncthreads();
    double v = 0.0;
    if (t < 96) {
        v = wsd[WSD_ACC + t];
        if (t < 32)       v *= wfac;    // XX weighted
        else if (t >= 64) v = -v;       // -(XY+YX)
    }
    sred[t] = v; __syncthreads();
    for (int off = 64; off; off >>= 1) { if (t < off) sred[t] += sred[t + off]; __syncthreads(); }
    if (t == 0) {
        double inv = 1.0 / ((double)NB * (double)NB);
        out[0] = (float)(sred[0] * inv);
    }
}

extern "C" void kernel_launch(void* const* d_in, const int* in_sizes, int n_in,
                              void* d_out, int out_size, void* d_ws, size_t ws_size,
                              hipStream_t stream) {
    const float* src = (const float*)d_in[0];
    const float* tgt = (const float*)d_in[1];
    const float* s1  = (const float*)d_in[2];
    const float* s2  = (const float*)d_in[3];
    float* out = (float*)d_out;

    char* ws = (char*)d_ws;
    double* wsd = (double*)ws;
    float* sq = (float*)(ws + WS_SQ_OFF);
    unsigned short* tot = (unsigned short*)(ws + WS_TOT_OFF);

    // Zero slot header every call (harness poisons d_ws with 0xAA — R10 lesson).
    hipMemsetAsync(ws, 0, 2048, stream);

    hipLaunchKernelGGL(k_rows, dim3(NTOT/4), dim3(256), 0, stream,
                       src, tgt, s1, s2, sq, tot, wsd);
    hipLaunchKernelGGL(k_mmd,  dim3(NTRI),   dim3(256), 0, stream, tot, sq, wsd);
    hipLaunchKernelGGL(k_final, dim3(1),     dim3(128), 0, stream, wsd, out);
}

// Round 20
// 58.199 us; speedup vs baseline: 1.1861x; 1.0360x over previous
//
#include <hip/hip_runtime.h>
#include <hip/hip_bf16.h>
#include <stdint.h>

// Problem constants
#define NB   4096      // rows per input matrix
#define DTOT 256       // feature dim
#define NTOT 8192      // 2*NB
#define NBLK 64        // 8192 / 128 tile blocks per side
#define NTRI (NBLK * (NBLK + 1) / 2)   // 2080, divisible by 8
#define NXCD 8
#define CPX  (NTRI / NXCD)             // 260 tiles per XCD

// Workspace layout (bytes):  [first 2048 bytes zeroed by hipMemsetAsync each launch]
//   wsd[0..32)    S partial slots   (sum of row sq-norms)
//   wsd[32..64)   Sw partial slots  (sum of sigmoid(|s1-s2|))
//   wsd[64..160)  acc slots: [q*32 + s], q=0:XX 1:YY 2:XY+YX
//   ws+4096       float sq[8192]            (32 KB)
//   ws+36864      ushort tot[8192*256] bf16 (4 MB)
#define WSD_S     0
#define WSD_SW    32
#define WSD_ACC   64
#define WS_SQ_OFF  4096
#define WS_TOT_OFF 36864

typedef __attribute__((ext_vector_type(8))) short bf16x8;
typedef __attribute__((ext_vector_type(4))) float f32x4;

__device__ __forceinline__ unsigned short f2bf(float f) {
    unsigned int u = __float_as_uint(f);
    unsigned int r = (u + 0x7FFFu + ((u >> 16) & 1u)) >> 16;   // RNE
    return (unsigned short)r;
}

// ---------------- kernel A: row sq-norms + bf16 convert + slot partials ----------------
__global__ __launch_bounds__(256) void k_rows(const float* __restrict__ src,
                                              const float* __restrict__ tgt,
                                              const float* __restrict__ s1,
                                              const float* __restrict__ s2,
                                              float* __restrict__ sq,
                                              unsigned short* __restrict__ tot,
                                              double* __restrict__ wsd) {
    __shared__ double sred[4];
    int tid  = threadIdx.x;
    int lane = tid & 63;
    int wid  = tid >> 6;
    int r = blockIdx.x * 4 + wid;
    const float* p = (r < NB) ? (src + (size_t)r * DTOT)
                              : (tgt + (size_t)(r - NB) * DTOT);
    float4 v = *(const float4*)(p + lane * 4);
    float s = v.x * v.x + v.y * v.y + v.z * v.z + v.w * v.w;
    ushort4 u;
    u.x = f2bf(v.x); u.y = f2bf(v.y); u.z = f2bf(v.z); u.w = f2bf(v.w);
    *(ushort4*)(tot + (size_t)r * DTOT + lane * 4) = u;
    for (int off = 32; off; off >>= 1) s += __shfl_down(s, off, 64);
    if (lane == 0) { sq[r] = s; sred[wid] = (double)s; }
    __syncthreads();
    if (tid == 0) {
        atomicAdd(&wsd[WSD_S + (blockIdx.x & 31)],
                  sred[0] + sred[1] + sred[2] + sred[3]);
        if (blockIdx.x < NB / 4) {
            float sw = 0.0f;
#pragma unroll
            for (int j = 0; j < 4; ++j) {
                int i = blockIdx.x * 4 + j;
                float d = fabsf(s1[i] - s2[i]);
                sw += 1.0f / (1.0f + exp2f(-d * 1.442695041f));
            }
            atomicAdd(&wsd[WSD_SW + (blockIdx.x & 31)], (double)sw);
        }
    }
}

// ---------------- kernel C: fused GEMM + RBF epilogue, upper-tri ----------------------
// R17 VERBATIM — the measured best (57.5 us) of all tested structural families:
//   single-buffer(R13,59.8) / dbuf-BK64(R14,63.1) / THIS dbuf-BK32-full-occ(R17,57.5) /
//   barrier-free(R18,69.0) / thin-wave(R11,456) / pipeline-graft(R9,80.7) /
//   fence-fusion(R12,335.8).
// BK=32 double-buffered pipeline at FULL occupancy: LDS = 2 bufs x (A+B) x 128x32 bf16
// = 32 KB -> 4 blocks/CU (VGPR-capped at 16 waves/CU: acc[4][4]=64 f32 floor).
// 8 K-steps; each issues next step's 4 global_load_lds then waits vmcnt(4) (counted:
// new loads fly across the barrier under current MFMAs).
// LDS packing: logical (r,c4) r=0..127, chunk c4=0..3 -> LDS row r&63, chunk
// ((r>>6)*4+c4)^((r&63)&7): 8-chunk XOR geometry, 2-way-free. Swizzle on per-lane
// global SOURCE (rule 21), linear global_load_lds dest, matching XOR on ds_read.
// T1 XCD-chunked blockIdx swizzle kept (R15).
// HARD-WON LESSONS — do not reintroduce:
//   R6/R7: launch_bounds min-waves arg -> accumulator spill.  R11: 512-thr -> VGPR 36.
//   R12: per-thread __threadfence ticket -> L2 flush storm.   R18: barrier-free single-
//   buffer waves -> full latency exposure every K-step.
//   R19: prefetching epilogue sq[]/S-slot loads BEFORE the K-loop corrupts the counted
//        vmcnt FIFO (their un-consumed loads must drain at the first vmcnt(4)) -> 60.3.
//        Epilogue inputs must stay AFTER the loop.
__global__ __launch_bounds__(256) void k_mmd(const unsigned short* __restrict__ tot,
                                             const float* __restrict__ sq,
                                             double* __restrict__ wsd) {
    __shared__ unsigned short lds[2][2][64 * 64];   // [buf][A=0,B=1][rr*64 + chunk*8]

    // T1: XCD-chunked swizzle, then decode upper-triangular index t -> (bi, bj), bi <= bj
    const int t = (blockIdx.x % NXCD) * CPX + blockIdx.x / NXCD;
    int bi = (int)((2.0f * NBLK + 1.0f
                    - sqrtf((2.0f * NBLK + 1.0f) * (2.0f * NBLK + 1.0f) - 8.0f * (float)t)) * 0.5f);
    while (bi > 0 && bi * (2 * NBLK - bi + 1) / 2 > t) --bi;
    while ((bi + 1) * (2 * NBLK - bi) / 2 <= t) ++bi;
    const int bj = bi + (t - bi * (2 * NBLK - bi + 1) / 2);

    const int tid  = threadIdx.x;
    const int lane = tid & 63;
    const int wid  = tid >> 6;
    const int wm = wid >> 1, wn = wid & 1;
    const int brow = bi * 128;
    const int bcol = bj * 128;

    const unsigned short* gA = tot + (size_t)brow * DTOT;
    const unsigned short* gB = tot + (size_t)bcol * DTOT;

    f32x4 acc[4][4] = {};

    // ---- per-lane staging geometry (ki-invariant) ----
    int rr_0 = (wid * 2 + 0) * 8 + (lane >> 3);
    int g_0  = (lane & 7) ^ (rr_0 & 7);
    const size_t srcOff0 = (size_t)(rr_0 + 64 * (g_0 >> 2)) * DTOT + (g_0 & 3) * 8;
    const int dst0 = (wid * 2 + 0) * 8 * 64;
    int rr_1 = (wid * 2 + 1) * 8 + (lane >> 3);
    int g_1  = (lane & 7) ^ (rr_1 & 7);
    const size_t srcOff1 = (size_t)(rr_1 + 64 * (g_1 >> 2)) * DTOT + (g_1 & 3) * 8;
    const int dst1 = (wid * 2 + 1) * 8 * 64;

#define STAGE(buf, ki_)                                                           \
    do {                                                                          \
        const int c0_ = (ki_) * 32;                                               \
        __builtin_amdgcn_global_load_lds(                                         \
            (const __attribute__((address_space(1))) void*)(gA + srcOff0 + c0_),  \
            (__attribute__((address_space(3))) void*)(&lds[buf][0][dst0]), 16, 0, 0); \
        __builtin_amdgcn_global_load_lds(                                         \
            (const __attribute__((address_space(1))) void*)(gA + srcOff1 + c0_),  \
            (__attribute__((address_space(3))) void*)(&lds[buf][0][dst1]), 16, 0, 0); \
        __builtin_amdgcn_global_load_lds(                                         \
            (const __attribute__((address_space(1))) void*)(gB + srcOff0 + c0_),  \
            (__attribute__((address_space(3))) void*)(&lds[buf][1][dst0]), 16, 0, 0); \
        __builtin_amdgcn_global_load_lds(                                         \
            (const __attribute__((address_space(1))) void*)(gB + srcOff1 + c0_),  \
            (__attribute__((address_space(3))) void*)(&lds[buf][1][dst1]), 16, 0, 0); \
    } while (0)

    // ---- per-lane read geometry (ki-invariant LDS offsets, in shorts) ----
    int rdA[4], rdB[4];
#pragma unroll
    for (int mi = 0; mi < 4; ++mi) {
        int rr = mi * 16 + (lane & 15);
        rdA[mi] = rr * 64 + (((wm * 4 + (lane >> 4)) ^ (rr & 7)) * 8);
        rdB[mi] = rr * 64 + (((wn * 4 + (lane >> 4)) ^ (rr & 7)) * 8);
    }

    STAGE(0, 0);                       // prologue: 4 loads in flight
#pragma unroll
    for (int ki = 0; ki < 8; ++ki) {
        const int cur = ki & 1;
        if (ki < 7) {
            STAGE(cur ^ 1, ki + 1);    // 4 more in flight (other buffer)
            asm volatile("s_waitcnt vmcnt(4)" ::: "memory");   // current step landed
        } else {
            asm volatile("s_waitcnt vmcnt(0)" ::: "memory");
        }
        __builtin_amdgcn_sched_barrier(0);
        __builtin_amdgcn_s_barrier();          // raw: no implicit vmcnt(0) drain

        const unsigned short* la = &lds[cur][0][0];
        const unsigned short* lb = &lds[cur][1][0];
        bf16x8 af[4], bfr[4];
#pragma unroll
        for (int mi = 0; mi < 4; ++mi) af[mi]  = *(const bf16x8*)(la + rdA[mi]);
#pragma unroll
        for (int ni = 0; ni < 4; ++ni) bfr[ni] = *(const bf16x8*)(lb + rdB[ni]);
#pragma unroll
        for (int mi = 0; mi < 4; ++mi)
#pragma unroll
            for (int ni = 0; ni < 4; ++ni)
                acc[mi][ni] = __builtin_amdgcn_mfma_f32_16x16x32_bf16(
                    af[mi], bfr[ni], acc[mi][ni], 0, 0, 0);

        __builtin_amdgcn_s_barrier();          // all waves done reading lds[cur]
    }
#undef STAGE

    // ---- derive bandwidth scale from S-slots (per-wave, no barrier) ----
    double sv = (lane < 32) ? wsd[WSD_S + lane] : 0.0;
#pragma unroll
    for (int off = 32; off; off >>= 1) sv += __shfl_down(sv, off, 64);
    sv = __shfl(sv, 0, 64);                          // S total, broadcast
    const float c = (float)(1.4426950408889634
                            * ((double)NTOT * (double)NTOT - (double)NTOT)
                            / (8.0 * (double)NTOT * sv));
    const float c2 = 2.0f * c;

    // ---- fused epilogue: L2 -> 5-bandwidth RBF sum -> quadrant accumulate ----
    float sqjc[4], sqic[16];
#pragma unroll
    for (int ni = 0; ni < 4; ++ni)
        sqjc[ni] = sq[bcol + wn * 64 + ni * 16 + (lane & 15)] * c;
#pragma unroll
    for (int mi = 0; mi < 4; ++mi)
#pragma unroll
        for (int r = 0; r < 4; ++r)
            sqic[mi * 4 + r] = sq[brow + wm * 64 + mi * 16 + (lane >> 4) * 4 + r] * c;

    float part = 0.0f;
#pragma unroll
    for (int mi = 0; mi < 4; ++mi) {
#pragma unroll
        for (int ni = 0; ni < 4; ++ni) {
#pragma unroll
            for (int r = 0; r < 4; ++r) {
                float s  = sqic[mi * 4 + r] + sqjc[ni];
                float tn = fminf(__builtin_fmaf(c2, acc[mi][ni][r], -s), 0.0f);
                float k4 = __builtin_amdgcn_exp2f(tn);     // raw v_exp_f32
                float k3 = k4 * k4;
                float k2 = k3 * k3;
                float k1 = k2 * k2;
                float k0 = k1 * k1;
                part += ((k4 + k3) + (k2 + k1)) + k0;
            }
        }
    }
    for (int off = 32; off; off >>= 1) part += __shfl_down(part, off, 64);

    // block reduce: alias scratch into lds (free after the loop's final barrier)
    double* blkred = (double*)&lds[0][0][0];
    if (lane == 0) blkred[wid] = (double)part;
    __syncthreads();
    if (tid == 0) {
        double tsum = blkred[0] + blkred[1] + blkred[2] + blkred[3];
        if (bi != bj) tsum *= 2.0;                     // transpose block identical
        int qi = (brow < NB) ? ((bcol < NB) ? 0 : 2) : 1;
        atomicAdd(&wsd[WSD_ACC + qi * 32 + (t & 31)], tsum);
    }
}

// ---------------- kernel D: finalize (wfac from Sw-slots, then acc reduce) ------------
__global__ __launch_bounds__(128) void k_final(const double* __restrict__ wsd,
                                               float* __restrict__ out) {
    __shared__ double sred[128];
    int t = threadIdx.x;
    sred[t] = (t < 32) ? wsd[WSD_SW + t] : 0.0;
    __syncthreads();
    for (int off = 64; off; off >>= 1) { if (t < off) sred[t] += sred[t + off]; __syncthreads(); }
    double Sw = sred[0];
    double SW = Sw * Sw;
    double wfac = SW / (SW + 1e-8);
    __syncthreads();
    double v = 0.0;
    if (t < 96) {
        v = wsd[WSD_ACC + t];
        if (t < 32)       v *= wfac;    // XX weighted
        else if (t >= 64) v = -v;       // -(XY+YX)
    }
    sred[t] = v; __syncthreads();
    for (int off = 64; off; off >>= 1) { if (t < off) sred[t] += sred[t + off]; __syncthreads(); }
    if (t == 0) {
        double inv = 1.0 / ((double)NB * (double)NB);
        out[0] = (float)(sred[0] * inv);
    }
}

extern "C" void kernel_launch(void* const* d_in, const int* in_sizes, int n_in,
                              void* d_out, int out_size, void* d_ws, size_t ws_size,
                              hipStream_t stream) {
    const float* src = (const float*)d_in[0];
    const float* tgt = (const float*)d_in[1];
    const float* s1  = (const float*)d_in[2];
    const float* s2  = (const float*)d_in[3];
    float* out = (float*)d_out;

    char* ws = (char*)d_ws;
    double* wsd = (double*)ws;
    float* sq = (float*)(ws + WS_SQ_OFF);
    unsigned short* tot = (unsigned short*)(ws + WS_TOT_OFF);

    // Zero slot header every call (harness poisons d_ws with 0xAA — R10 lesson).
    hipMemsetAsync(ws, 0, 2048, stream);

    hipLaunchKernelGGL(k_rows, dim3(NTOT/4), dim3(256), 0, stream,
                       src, tgt, s1, s2, sq, tot, wsd);
    hipLaunchKernelGGL(k_mmd,  dim3(NTRI),   dim3(256), 0, stream, tot, sq, wsd);
    hipLaunchKernelGGL(k_final, dim3(1),     dim3(128), 0, stream, wsd, out);
}